// Round 12
// baseline (337.753 us; speedup 1.0000x reference)
//
#include <hip/hip_runtime.h>
#include <hip/hip_bf16.h>

// GNNBackbone: x[B,1000] ⊙ emb[1000,128] -> 3×(GCN+relu) -> mean over D.
// Edges only touch nodes [0,1000) = batch 0. For b>=1 each layer is row-local:
// h <- relu(h@W^T + b). TWO nodes:
//  k_prep: emb/E1 MFMA two-stage + weight cvt + zeroing.
//  k_mega: [0,125) edge scatter -> signal; [125,1149) R9-proven k_big compute
//          (2 batches/block, both weights LDS, 50us); [1149,1649) batch-0
//          chain: 500 blocks (2000 waves = k_layer-equivalent parallelism),
//          spin on scatter signal, then L1 -> bar -> L2 -> bar -> L3-pool.
#define B_N 256
#define D_N 1000
#define H_N 128
#define E_N 32000
#define CAP 128    // in-degree capacity (Poisson(32), max ~65 observed)
#define CHN 500    // chain blocks (<= 512 co-residency slots at 64KB LDS)
#define CHB 1149   // chain block base

typedef unsigned int uint32;
typedef unsigned short u16;
typedef __attribute__((ext_vector_type(8))) short bf16x8;
typedef __attribute__((ext_vector_type(4))) float f32x4;

__device__ __forceinline__ u16 f2bf(float f) {
    union { float f; uint32 u; } v; v.f = f;
    return (u16)((v.u + 0x7fffu + ((v.u >> 16) & 1u)) >> 16);  // RNE
}
__device__ __forceinline__ uint32 pk2(float lo, float hi) {    // v_cvt_pk_bf16_f32
    __hip_bfloat162 h = __float22bfloat162_rn(make_float2(lo, hi));
    union { __hip_bfloat162 h; uint32 u; } v; v.h = h; return v.u;
}
__device__ __forceinline__ float asf(uint32 u) {
    union { uint32 u; float f; } v; v.u = u; return v.f;
}
__device__ __forceinline__ float rl(float x) { return x > 0.f ? x : 0.f; }

// load 8 floats at p (absolute k index kbase), zero-padded past k=300
__device__ __forceinline__ void ld8g(const float* __restrict__ p, int kbase, float v[8]) {
    if (kbase + 8 <= 300) {
        float4 a = *(const float4*)p, b = *(const float4*)(p + 4);
        v[0] = a.x; v[1] = a.y; v[2] = a.z; v[3] = a.w;
        v[4] = b.x; v[5] = b.y; v[6] = b.z; v[7] = b.w;
    } else {
#pragma unroll
        for (int j = 0; j < 8; ++j) v[j] = (kbase + j < 300) ? p[j] : 0.f;
    }
}

// build a bf16x8 h1 A-fragment: relu(xv * e + b0slice)
__device__ __forceinline__ bf16x8 mk_h1(float xv, uint4 e, float4 bl, float4 bh) {
    float v0 = rl(fmaf(xv, asf(e.x << 16), bl.x));
    float v1 = rl(fmaf(xv, asf(e.x & 0xffff0000u), bl.y));
    float v2 = rl(fmaf(xv, asf(e.y << 16), bl.z));
    float v3 = rl(fmaf(xv, asf(e.y & 0xffff0000u), bl.w));
    float v4 = rl(fmaf(xv, asf(e.z << 16), bh.x));
    float v5 = rl(fmaf(xv, asf(e.z & 0xffff0000u), bh.y));
    float v6 = rl(fmaf(xv, asf(e.w << 16), bh.z));
    float v7 = rl(fmaf(xv, asf(e.w & 0xffff0000u), bh.w));
    uint4 pk = { pk2(v0, v1), pk2(v2, v3), pk2(v4, v5), pk2(v6, v7) };
    return *(const bf16x8*)&pk;
}

// ---------------------------------------------------------------------------
// k_prep: blocks [0,63)   : MFMA two-stage, 16 d-rows/block:
//                           emb = V@W_embed^T + b_embed (K=300 bf16, padded),
//                           LDS transpose, E1 = emb@W0^T -> E1h bf16 + t0 f32.
//         blocks [63,127) : W1/W2 -> bf16
//         blocks [127,255): zero out[256*128]
//         block  255      : zero deg + zero bar counters
// ---------------------------------------------------------------------------
__global__ void k_prep(const float* __restrict__ V, const float* __restrict__ W_embed,
                       const float* __restrict__ b_embed, const float* __restrict__ W0,
                       const float* __restrict__ Xn, const float* __restrict__ Xc,
                       const float* __restrict__ W1, const float* __restrict__ W2,
                       int* __restrict__ deg, int* __restrict__ bar,
                       u16* __restrict__ w1h, u16* __restrict__ w2h,
                       u16* __restrict__ E1h, float* __restrict__ t0,
                       float* __restrict__ out) {
    __shared__ __align__(16) u16 sW0[128 * 128];   // 32 KiB: W0 bf16, swizzled
    __shared__ __align__(16) u16 sWc[128 * 64];    // 16 KiB: W_embed k-chunk
    __shared__ __align__(16) u16 sVc[16 * 64];     //  2 KiB: V k-chunk
    __shared__ __align__(16) u16 sT[16 * 128];     //  4 KiB: emb transpose

    int bid = blockIdx.x, tid = threadIdx.x;
    if (bid >= 63) {
        if (bid < 127) {
            int i = (bid - 63) * 256 + tid;            // 0..16383 exact
            w1h[i] = f2bf(W1[i]); w2h[i] = f2bf(W2[i]);
        } else if (bid < 255) {
            int i = (bid - 127) * 256 + tid;           // 0..32767 exact
            out[i] = 0.f;
        } else {
            for (int j = tid; j < D_N; j += 256) deg[j] = 0;
            if (tid < 16) bar[tid] = 0;                // barrier counters zeroed
        }
        return;
    }

    const int wave = tid >> 6, lane = tid & 63;
    const int quad = lane >> 4, l15 = lane & 15;
    const int nh = wave;                 // each wave owns 32 output cols
    const int dbase = bid * 16;          // 63*16 = 1008 >= 1000

    // ---- W0 f32 -> sW0 bf16 (swizzled granules) ----
#pragma unroll
    for (int ii = 0; ii < 8; ++ii) {
        int idx = tid + ii * 256;                  // 2048 granules
        int row = idx >> 4, g = idx & 15;
        float4 a = *(const float4*)(W0 + row * 128 + g * 8);
        float4 b = *(const float4*)(W0 + row * 128 + g * 8 + 4);
        uint4 pk = { pk2(a.x, a.y), pk2(a.z, a.w), pk2(b.x, b.y), pk2(b.z, b.w) };
        *(uint4*)&sW0[row * 128 + ((g ^ (row & 7)) << 3)] = pk;
    }

    // ---- stage A: emb = V @ W_embed^T over 5 k-chunks of 64 ----
    f32x4 accA[2];
#pragma unroll
    for (int n = 0; n < 2; ++n) { accA[n][0] = 0.f; accA[n][1] = 0.f; accA[n][2] = 0.f; accA[n][3] = 0.f; }

    for (int ck = 0; ck < 5; ++ck) {
        int k0 = ck * 64;
        if (tid < 128) {
            int row = tid >> 3, seg = tid & 7;
            int d = dbase + row; int dc = d < D_N ? d : D_N - 1;
            int kk = k0 + seg * 8;
            float v[8]; ld8g(V + dc * 300 + kk, kk, v);
            uint4 pk = { pk2(v[0], v[1]), pk2(v[2], v[3]), pk2(v[4], v[5]), pk2(v[6], v[7]) };
            *(uint4*)&sVc[row * 64 + ((seg ^ (row & 7)) << 3)] = pk;
        }
#pragma unroll
        for (int gg = 0; gg < 4; ++gg) {
            int idx = tid + gg * 256;
            int row = idx >> 3, g = idx & 7;
            int kk = k0 + g * 8;
            float v[8]; ld8g(W_embed + row * 300 + kk, kk, v);
            uint4 pk = { pk2(v[0], v[1]), pk2(v[2], v[3]), pk2(v[4], v[5]), pk2(v[6], v[7]) };
            *(uint4*)&sWc[row * 64 + ((g ^ (row & 7)) << 3)] = pk;
        }
        __syncthreads();
#pragma unroll
        for (int ksb = 0; ksb < 2; ++ksb) {
            int g = ksb * 4 + quad;
            bf16x8 av = *(const bf16x8*)&sVc[l15 * 64 + ((g ^ (l15 & 7)) << 3)];
#pragma unroll
            for (int n = 0; n < 2; ++n) {
                int br = nh * 32 + n * 16 + l15;
                bf16x8 bv = *(const bf16x8*)&sWc[br * 64 + ((g ^ (br & 7)) << 3)];
                accA[n] = __builtin_amdgcn_mfma_f32_16x16x32_bf16(av, bv, accA[n], 0, 0, 0);
            }
        }
        __syncthreads();   // WAR on chunk buffers
    }

    // ---- + b_embed, pair-packed transpose into sT ----
    {
        const int odd = l15 & 1;
#pragma unroll
        for (int n = 0; n < 2; ++n) {
            float bb = b_embed[nh * 32 + n * 16 + l15];
            float v0 = accA[n][0] + bb, v1 = accA[n][1] + bb;
            float v2 = accA[n][2] + bb, v3 = accA[n][3] + bb;
            float t0_ = __shfl_xor(v0, 1), t1_ = __shfl_xor(v1, 1);
            float t2_ = __shfl_xor(v2, 1), t3_ = __shfl_xor(v3, 1);
            float lo0 = odd ? t2_ : v0, hi0 = odd ? v2 : t0_;
            float lo1 = odd ? t3_ : v1, hi1 = odd ? v3 : t1_;
            int r0 = quad * 4 + (odd ? 2 : 0);
            int r1 = r0 + 1;
            int ce = nh * 32 + n * 16 + (l15 & ~1);
            *(uint32*)&sT[r0 * 128 + (((ce >> 3) ^ (r0 & 7)) << 3) + (ce & 7)] = pk2(lo0, hi0);
            *(uint32*)&sT[r1 * 128 + (((ce >> 3) ^ (r1 & 7)) << 3) + (ce & 7)] = pk2(lo1, hi1);
        }
    }
    __syncthreads();   // sT (cross-wave k-reads) + sW0 visible

    // ---- stage B: E1 = emb @ W0^T (K=128) ----
    f32x4 accB[2];
#pragma unroll
    for (int n = 0; n < 2; ++n) { accB[n][0] = 0.f; accB[n][1] = 0.f; accB[n][2] = 0.f; accB[n][3] = 0.f; }
#pragma unroll
    for (int ks = 0; ks < 4; ++ks) {
        int g = ks * 4 + quad;
        bf16x8 av = *(const bf16x8*)&sT[l15 * 128 + ((g ^ (l15 & 7)) << 3)];
#pragma unroll
        for (int n = 0; n < 2; ++n) {
            int br = nh * 32 + n * 16 + l15;
            bf16x8 bv = *(const bf16x8*)&sW0[br * 128 + ((g ^ (br & 7)) << 3)];
            accB[n] = __builtin_amdgcn_mfma_f32_16x16x32_bf16(av, bv, accB[n], 0, 0, 0);
        }
    }

    // ---- epilogue: E1h bf16 + t0 = x0*E1 (rows d < 1000 only) ----
#pragma unroll
    for (int i = 0; i < 4; ++i) {
        int r = quad * 4 + i;
        int d = dbase + r;
        if (d < D_N) {
            float x0 = (d < 800) ? Xn[d] : Xc[d - 800];
#pragma unroll
            for (int n = 0; n < 2; ++n) {
                int col = nh * 32 + n * 16 + l15;
                float e1 = accB[n][i];
                E1h[d * H_N + col] = f2bf(e1);
                t0[d * H_N + col] = x0 * e1;
            }
        }
    }
}

// ---------------------------------------------------------------------------
// k_mega:
//  blocks [0,125)    : edge scatter (coalesced) -> fence -> bar[0] += 1
//  blocks [125,1149) : R9-proven k_big compute: 128 batch-pairs x 8 chunks,
//                      both weights LDS, h1 in regs, 2 batches/block (50us).
//  blocks [1149,1649): batch-0 chain, 500 blocks x 4 waves (= k_layer's 2000
//                      waves). Spin-acquire bar[0]==125, then:
//                      L1(t0->t1) -> bar1(500) -> L2(t1->t2) -> bar2(500)
//                      -> L3 agg+relu+mean-pool into out[0,:].
// Deadlock audit: chain blocks are last in dispatch order; 500 <= 512 LDS
// co-residency slots; compute/scatter blocks never wait => slots always free.
// Barriers: plain stores + __threadfence (device scope) + agent acq/rel
// atomics (R7-proven correct cross-XCD on this HW).
// MFMA 16x16x32 bf16 layouts (m89/m120-verified):
//   A/B: lane holds M[row=lane&15][k=quad*8+j]; C/D: col=lane&15, row=quad*4+reg
// ---------------------------------------------------------------------------
__global__ __launch_bounds__(256, 2)
void k_mega(const float* __restrict__ Xn, const float* __restrict__ Xc,
            const u16* __restrict__ E1h, const u16* __restrict__ w1h,
            const u16* __restrict__ w2h, const float* __restrict__ b0,
            const float* __restrict__ b1, const float* __restrict__ b2,
            const float* __restrict__ W1, const float* __restrict__ W2,
            const int* __restrict__ eidx, int* __restrict__ deg,
            int* __restrict__ es, const float* __restrict__ t0,
            float* __restrict__ t1, float* __restrict__ t2,
            int* bar, float* __restrict__ out) {
    __shared__ __align__(16) u16 sA[128 * 128];   // 32 KiB
    __shared__ __align__(16) u16 sB[128 * 128];   // 32 KiB

    const int bid = blockIdx.x, tid = threadIdx.x;

    // ================= scatter blocks =================
    if (bid < 125) {
        int i = bid * 256 + tid;                   // 0..31999 exact
        int s = eidx[i], t = eidx[E_N + i];
        int pos = atomicAdd(&deg[t], 1);
        if (pos < CAP) es[t * CAP + pos] = s;
        __syncthreads();
        if (tid == 0) {
            __threadfence();
            __hip_atomic_fetch_add(bar, 1, __ATOMIC_ACQ_REL, __HIP_MEMORY_SCOPE_AGENT);
        }
        return;
    }

    // ================= k_big compute blocks (R9-proven) =================
    if (bid < CHB) {
        const int cb = bid - 125;
        const int wave = tid >> 6, lane = tid & 63;
        const int quad = lane >> 4, l15 = lane & 15;
        const int pr = cb >> 3;
        const int bi0 = 1 + 2 * pr;
        const int bi1 = 2 + 2 * pr;
        const int wr1 = bi1 < B_N;
        const int bi1c = wr1 ? bi1 : B_N - 1;
        const int mbase = ((cb & 7) << 7) + wave * 32;
        u16* hw = sA + wave * (32 * 128);

        {
            const uint4* w1v = (const uint4*)w1h;
            const uint4* w2v = (const uint4*)w2h;
#pragma unroll
            for (int i = 0; i < 8; ++i) {
                int idx = tid + i * 256;
                int row = idx >> 4, g = idx & 15;
                int off = row * 128 + ((g ^ (row & 7)) << 3);
                *(uint4*)&sA[off] = w1v[idx];
                *(uint4*)&sB[off] = w2v[idx];
            }
        }

        const int rA = mbase + l15;  const int rAc = rA < D_N ? rA : D_N - 1;
        const int rB = rA + 16;      const int rBc = rB < D_N ? rB : D_N - 1;
        const float xv0A = (rAc < 800) ? Xn[bi0 * 800 + rAc] : Xc[bi0 * 200 + rAc - 800];
        const float xv0B = (rBc < 800) ? Xn[bi0 * 800 + rBc] : Xc[bi0 * 200 + rBc - 800];
        const float xv1A = (rAc < 800) ? Xn[bi1c * 800 + rAc] : Xc[bi1c * 200 + rAc - 800];
        const float xv1B = (rBc < 800) ? Xn[bi1c * 800 + rBc] : Xc[bi1c * 200 + rBc - 800];

        f32x4 acc0[2][8], acc1[2][8];
#pragma unroll
        for (int rt = 0; rt < 2; ++rt)
#pragma unroll
            for (int n = 0; n < 8; ++n) {
                acc0[rt][n][0] = 0.f; acc0[rt][n][1] = 0.f; acc0[rt][n][2] = 0.f; acc0[rt][n][3] = 0.f;
                acc1[rt][n][0] = 0.f; acc1[rt][n][1] = 0.f; acc1[rt][n][2] = 0.f; acc1[rt][n][3] = 0.f;
            }

        __syncthreads();   // weights staged

#pragma unroll
        for (int ks = 0; ks < 4; ++ks) {
            const int k8 = ks * 4 + quad;
            uint4 eA = *(const uint4*)(E1h + rAc * H_N + k8 * 8);
            uint4 eB = *(const uint4*)(E1h + rBc * H_N + k8 * 8);
            float4 bl = *(const float4*)(b0 + k8 * 8);
            float4 bh = *(const float4*)(b0 + k8 * 8 + 4);
            bf16x8 a0A = mk_h1(xv0A, eA, bl, bh);
            bf16x8 a0B = mk_h1(xv0B, eB, bl, bh);
            bf16x8 a1A = mk_h1(xv1A, eA, bl, bh);
            bf16x8 a1B = mk_h1(xv1B, eB, bl, bh);
#pragma unroll
            for (int n = 0; n < 8; ++n) {
                int br = n * 16 + l15;
                bf16x8 bw = *(const bf16x8*)&sA[br * 128 + ((k8 ^ (br & 7)) << 3)];
                acc0[0][n] = __builtin_amdgcn_mfma_f32_16x16x32_bf16(a0A, bw, acc0[0][n], 0, 0, 0);
                acc0[1][n] = __builtin_amdgcn_mfma_f32_16x16x32_bf16(a0B, bw, acc0[1][n], 0, 0, 0);
                acc1[0][n] = __builtin_amdgcn_mfma_f32_16x16x32_bf16(a1A, bw, acc1[0][n], 0, 0, 0);
                acc1[1][n] = __builtin_amdgcn_mfma_f32_16x16x32_bf16(a1B, bw, acc1[1][n], 0, 0, 0);
            }
        }

        __syncthreads();   // all waves done reading W1 from sA

        const int rem = D_N - mbase;
        const int odd = l15 & 1;

#pragma unroll
        for (int bsel = 0; bsel < 2; ++bsel) {
            f32x4 (*accp)[8] = bsel ? acc1 : acc0;
            int bi = bsel ? bi1 : bi0;
            int wr = bsel ? wr1 : 1;

#pragma unroll
            for (int rt = 0; rt < 2; ++rt)
#pragma unroll
                for (int n = 0; n < 8; ++n) {
                    float bg = b1[n * 16 + l15];
                    float v0 = rl(accp[rt][n][0] + bg);
                    float v1 = rl(accp[rt][n][1] + bg);
                    float v2 = rl(accp[rt][n][2] + bg);
                    float v3 = rl(accp[rt][n][3] + bg);
                    float t0_ = __shfl_xor(v0, 1), t1_ = __shfl_xor(v1, 1);
                    float t2_ = __shfl_xor(v2, 1), t3_ = __shfl_xor(v3, 1);
                    float lo0 = odd ? t2_ : v0, hi0 = odd ? v2 : t0_;
                    float lo1 = odd ? t3_ : v1, hi1 = odd ? v3 : t1_;
                    int r0 = rt * 16 + quad * 4 + (odd ? 2 : 0);
                    int r1 = r0 + 1;
                    int ce = n * 16 + (l15 & ~1);
                    *(uint32*)&hw[r0 * 128 + (((ce >> 3) ^ (r0 & 7)) << 3) + (ce & 7)] = pk2(lo0, hi0);
                    *(uint32*)&hw[r1 * 128 + (((ce >> 3) ^ (r1 & 7)) << 3) + (ce & 7)] = pk2(lo1, hi1);
                }

#pragma unroll
            for (int rt = 0; rt < 2; ++rt)
#pragma unroll
                for (int n = 0; n < 8; ++n) {
                    accp[rt][n][0] = 0.f; accp[rt][n][1] = 0.f;
                    accp[rt][n][2] = 0.f; accp[rt][n][3] = 0.f;
                }
#pragma unroll
            for (int ks = 0; ks < 4; ++ks) {
                int k8 = ks * 4 + quad;
                int m0 = l15, m1 = 16 + l15;
                bf16x8 a0 = *(const bf16x8*)&hw[m0 * 128 + ((k8 ^ (m0 & 7)) << 3)];
                bf16x8 a1 = *(const bf16x8*)&hw[m1 * 128 + ((k8 ^ (m1 & 7)) << 3)];
#pragma unroll
                for (int n = 0; n < 8; ++n) {
                    int br = n * 16 + l15;
                    bf16x8 bw = *(const bf16x8*)&sB[br * 128 + ((k8 ^ (br & 7)) << 3)];
                    accp[0][n] = __builtin_amdgcn_mfma_f32_16x16x32_bf16(a0, bw, accp[0][n], 0, 0, 0);
                    accp[1][n] = __builtin_amdgcn_mfma_f32_16x16x32_bf16(a1, bw, accp[1][n], 0, 0, 0);
                }
            }

#pragma unroll
            for (int n = 0; n < 8; ++n) {
                float bg = b2[n * 16 + l15];
                float cs = 0.f;
#pragma unroll
                for (int rt = 0; rt < 2; ++rt)
#pragma unroll
                    for (int i = 0; i < 4; ++i) {
                        int r32 = rt * 16 + quad * 4 + i;
                        float v = rl(accp[rt][n][i] + bg);
                        if (r32 < rem) cs += v;
                    }
                cs += __shfl_xor(cs, 16);
                cs += __shfl_xor(cs, 32);
                if (lane < 16 && wr)
                    atomicAdd(&out[bi * H_N + n * 16 + l15], cs * (1.0f / 1000.0f));
            }
        }
        return;
    }

    // ================= chain blocks: batch-0 exact f32 =================
    {
        float* shf = (float*)sA;                   // 1 KiB of sA reused
        const int cj = bid - CHB;                  // 0..499
        const int half = tid >> 7, e = tid & 127;
        const int d = cj * 2 + half;               // 0..999

        // wait for scatter completion (deg/es ready)
        if (tid == 0) {
            while (__hip_atomic_load(bar, __ATOMIC_ACQUIRE, __HIP_MEMORY_SCOPE_AGENT) < 125)
                __builtin_amdgcn_s_sleep(8);
        }
        __syncthreads();

#define GBAR(c)                                                                      \
        __syncthreads();                                                             \
        if (tid == 0) {                                                              \
            __threadfence();                                                         \
            __hip_atomic_fetch_add(bar + (c), 1, __ATOMIC_ACQ_REL,                   \
                                   __HIP_MEMORY_SCOPE_AGENT);                        \
            while (__hip_atomic_load(bar + (c), __ATOMIC_ACQUIRE,                    \
                                     __HIP_MEMORY_SCOPE_AGENT) < CHN)                \
                __builtin_amdgcn_s_sleep(8);                                         \
        }                                                                            \
        __syncthreads();

        const float di = rsqrtf(1.f + (float)deg[d]);
        const int nn = deg[d] > CAP ? CAP : deg[d];
        const int* row = es + d * CAP;

        // ---- L1 and L2 ----
        for (int layer = 0; layer < 2; ++layer) {
            const float* tin  = layer ? t1 : t0;
            float*       tout = layer ? t2 : t1;
            const float* bb   = layer ? b1 : b0;
            const float* Wn   = layer ? W2 : W1;
            float acc = tin[d * H_N + e] * di * di;
            int i = 0;
            for (; i + 4 <= nn; i += 4) {
                int a0 = row[i], a1 = row[i + 1], a2 = row[i + 2], a3 = row[i + 3];
                float c0 = rsqrtf(1.f + (float)deg[a0]);
                float c1 = rsqrtf(1.f + (float)deg[a1]);
                float c2 = rsqrtf(1.f + (float)deg[a2]);
                float c3 = rsqrtf(1.f + (float)deg[a3]);
                acc += di * (c0 * tin[a0 * H_N + e] + c1 * tin[a1 * H_N + e] +
                             c2 * tin[a2 * H_N + e] + c3 * tin[a3 * H_N + e]);
            }
            for (; i < nn; ++i) {
                int s = row[i];
                acc += di * rsqrtf(1.f + (float)deg[s]) * tin[s * H_N + e];
            }
            float h = rl(acc + bb[e]);
            shf[tid] = h;
            __syncthreads();
            const float4* hr = (const float4*)(shf + half * 128);
            const float4* wr = (const float4*)(Wn + e * 128);
            float s = 0.f;
#pragma unroll 8
            for (int k = 0; k < 32; ++k) {
                float4 a = hr[k], w = wr[k];
                s += a.x * w.x + a.y * w.y + a.z * w.z + a.w * w.w;
            }
            tout[d * H_N + e] = s;
            if (layer == 0) { GBAR(1) } else { GBAR(2) }
        }

        // ---- L3: agg + relu + mean-pool into out[0,:] ----
        {
            float acc = t2[d * H_N + e] * di * di;
            for (int i = 0; i < nn; ++i) {
                int s = row[i];
                acc += di * rsqrtf(1.f + (float)deg[s]) * t2[s * H_N + e];
            }
            float h = rl(acc + b2[e]);
            shf[tid] = h;
            __syncthreads();
            if (half == 0)
                atomicAdd(&out[e], (shf[e] + shf[128 + e]) * (1.0f / 1000.0f));
        }
#undef GBAR
    }
}

// ---------------------------------------------------------------------------
extern "C" void kernel_launch(void* const* d_in, const int* in_sizes, int n_in,
                              void* d_out, int out_size, void* d_ws, size_t ws_size,
                              hipStream_t stream) {
    const float* Xn = (const float*)d_in[0];
    const float* Xc = (const float*)d_in[1];
    const float* V = (const float*)d_in[2];
    const int* eidx = (const int*)d_in[3];
    const float* W_embed = (const float*)d_in[4];
    const float* b_embed = (const float*)d_in[5];
    const float* W0 = (const float*)d_in[6];
    const float* b0 = (const float*)d_in[7];
    const float* W1 = (const float*)d_in[8];
    const float* b1 = (const float*)d_in[9];
    const float* W2 = (const float*)d_in[10];
    const float* b2 = (const float*)d_in[11];
    float* out = (float*)d_out;

    char* p = (char*)d_ws;
    auto alloc = [&](size_t bytes) -> char* {
        char* r = p;
        p += (bytes + 255) & ~(size_t)255;
        return r;
    };
    u16*   E1h = (u16*)  alloc(D_N * H_N * 2);
    float* t0  = (float*)alloc(D_N * H_N * 4);
    float* t1  = (float*)alloc(D_N * H_N * 4);
    float* t2  = (float*)alloc(D_N * H_N * 4);
    u16*   w1h = (u16*)  alloc(H_N * H_N * 2);
    u16*   w2h = (u16*)  alloc(H_N * H_N * 2);
    int*   deg = (int*)  alloc(D_N * 4);
    int*   es  = (int*)  alloc(D_N * CAP * 4);
    int*   bar = (int*)  alloc(64);

    k_prep<<<dim3(256), dim3(256), 0, stream>>>(V, W_embed, b_embed, W0, Xn, Xc,
                                                W1, W2, deg, bar, w1h, w2h, E1h, t0, out);
    k_mega<<<dim3(1649), dim3(256), 0, stream>>>(Xn, Xc, E1h, w1h, w2h, b0, b1, b2,
                                                 W1, W2, eidx, deg, es, t0, t1, t2,
                                                 bar, out);
}

// Round 13
// 184.877 us; speedup vs baseline: 1.8269x; 1.8269x over previous
//
#include <hip/hip_runtime.h>
#include <hip/hip_bf16.h>

// GNNBackbone: x[B,1000] ⊙ emb[1000,128] -> 3×(GCN+relu) -> mean over D.
// Edges only touch nodes [0,1000) = batch 0. For b>=1 each layer is row-local:
// h <- relu(h@W^T + b) => batches 1..255 in one fused bf16-MFMA kernel
// (R9-proven champion: both weights LDS, h1 in regs, 2 batches/block, edge
// scatter in first 125 blocks). Batch 0: exact f32 agg+gemm chain (3 nodes).
// NOTE (R7/R11/R12 evidence): all spin-barrier phase fusions regressed 1.4-2x
// vs this 5-node layout — do not reintroduce cross-block sync.
#define B_N 256
#define D_N 1000
#define H_N 128
#define E_N 32000
#define CAP 128   // in-degree capacity (Poisson(32), max ~65 observed)

typedef unsigned int uint32;
typedef unsigned short u16;
typedef __attribute__((ext_vector_type(8))) short bf16x8;
typedef __attribute__((ext_vector_type(4))) float f32x4;

__device__ __forceinline__ u16 f2bf(float f) {
    union { float f; uint32 u; } v; v.f = f;
    return (u16)((v.u + 0x7fffu + ((v.u >> 16) & 1u)) >> 16);  // RNE
}
__device__ __forceinline__ uint32 pk2(float lo, float hi) {    // v_cvt_pk_bf16_f32
    __hip_bfloat162 h = __float22bfloat162_rn(make_float2(lo, hi));
    union { __hip_bfloat162 h; uint32 u; } v; v.h = h; return v.u;
}
__device__ __forceinline__ float asf(uint32 u) {
    union { uint32 u; float f; } v; v.u = u; return v.f;
}
__device__ __forceinline__ float rl(float x) { return x > 0.f ? x : 0.f; }

// load 8 floats at p (absolute k index kbase), zero-padded past k=300
__device__ __forceinline__ void ld8g(const float* __restrict__ p, int kbase, float v[8]) {
    if (kbase + 8 <= 300) {
        float4 a = *(const float4*)p, b = *(const float4*)(p + 4);
        v[0] = a.x; v[1] = a.y; v[2] = a.z; v[3] = a.w;
        v[4] = b.x; v[5] = b.y; v[6] = b.z; v[7] = b.w;
    } else {
#pragma unroll
        for (int j = 0; j < 8; ++j) v[j] = (kbase + j < 300) ? p[j] : 0.f;
    }
}

// build a bf16x8 h1 A-fragment: relu(xv * e + b0slice)
__device__ __forceinline__ bf16x8 mk_h1(float xv, uint4 e, float4 bl, float4 bh) {
    float v0 = rl(fmaf(xv, asf(e.x << 16), bl.x));
    float v1 = rl(fmaf(xv, asf(e.x & 0xffff0000u), bl.y));
    float v2 = rl(fmaf(xv, asf(e.y << 16), bl.z));
    float v3 = rl(fmaf(xv, asf(e.y & 0xffff0000u), bl.w));
    float v4 = rl(fmaf(xv, asf(e.z << 16), bh.x));
    float v5 = rl(fmaf(xv, asf(e.z & 0xffff0000u), bh.y));
    float v6 = rl(fmaf(xv, asf(e.w << 16), bh.z));
    float v7 = rl(fmaf(xv, asf(e.w & 0xffff0000u), bh.w));
    uint4 pk = { pk2(v0, v1), pk2(v2, v3), pk2(v4, v5), pk2(v6, v7) };
    return *(const bf16x8*)&pk;
}

// ---------------------------------------------------------------------------
// k_prep: blocks [0,63)   : MFMA two-stage, 16 d-rows/block:
//                           emb = V@W_embed^T + b_embed (K=300 bf16, padded),
//                           LDS transpose, E1 = emb@W0^T -> E1h bf16 + t0 f32.
//         blocks [63,127) : W1/W2 -> bf16
//         blocks [127,255): zero out[256*128]
//         block  255      : zero deg (edge scatter runs inside k_big)
// ---------------------------------------------------------------------------
__global__ void k_prep(const float* __restrict__ V, const float* __restrict__ W_embed,
                       const float* __restrict__ b_embed, const float* __restrict__ W0,
                       const float* __restrict__ Xn, const float* __restrict__ Xc,
                       const float* __restrict__ W1, const float* __restrict__ W2,
                       int* __restrict__ deg,
                       u16* __restrict__ w1h, u16* __restrict__ w2h,
                       u16* __restrict__ E1h, float* __restrict__ t0,
                       float* __restrict__ out) {
    __shared__ __align__(16) u16 sW0[128 * 128];   // 32 KiB: W0 bf16, swizzled
    __shared__ __align__(16) u16 sWc[128 * 64];    // 16 KiB: W_embed k-chunk
    __shared__ __align__(16) u16 sVc[16 * 64];     //  2 KiB: V k-chunk
    __shared__ __align__(16) u16 sT[16 * 128];     //  4 KiB: emb transpose

    int bid = blockIdx.x, tid = threadIdx.x;
    if (bid >= 63) {
        if (bid < 127) {
            int i = (bid - 63) * 256 + tid;            // 0..16383 exact
            w1h[i] = f2bf(W1[i]); w2h[i] = f2bf(W2[i]);
        } else if (bid < 255) {
            int i = (bid - 127) * 256 + tid;           // 0..32767 exact
            out[i] = 0.f;
        } else {
            for (int j = tid; j < D_N; j += 256) deg[j] = 0;
        }
        return;
    }

    const int wave = tid >> 6, lane = tid & 63;
    const int quad = lane >> 4, l15 = lane & 15;
    const int nh = wave;                 // each wave owns 32 output cols
    const int dbase = bid * 16;          // 63*16 = 1008 >= 1000

    // ---- W0 f32 -> sW0 bf16 (swizzled granules) ----
#pragma unroll
    for (int ii = 0; ii < 8; ++ii) {
        int idx = tid + ii * 256;                  // 2048 granules
        int row = idx >> 4, g = idx & 15;
        float4 a = *(const float4*)(W0 + row * 128 + g * 8);
        float4 b = *(const float4*)(W0 + row * 128 + g * 8 + 4);
        uint4 pk = { pk2(a.x, a.y), pk2(a.z, a.w), pk2(b.x, b.y), pk2(b.z, b.w) };
        *(uint4*)&sW0[row * 128 + ((g ^ (row & 7)) << 3)] = pk;
    }

    // ---- stage A: emb = V @ W_embed^T over 5 k-chunks of 64 ----
    f32x4 accA[2];
#pragma unroll
    for (int n = 0; n < 2; ++n) { accA[n][0] = 0.f; accA[n][1] = 0.f; accA[n][2] = 0.f; accA[n][3] = 0.f; }

    for (int ck = 0; ck < 5; ++ck) {
        int k0 = ck * 64;
        if (tid < 128) {
            int row = tid >> 3, seg = tid & 7;
            int d = dbase + row; int dc = d < D_N ? d : D_N - 1;
            int kk = k0 + seg * 8;
            float v[8]; ld8g(V + dc * 300 + kk, kk, v);
            uint4 pk = { pk2(v[0], v[1]), pk2(v[2], v[3]), pk2(v[4], v[5]), pk2(v[6], v[7]) };
            *(uint4*)&sVc[row * 64 + ((seg ^ (row & 7)) << 3)] = pk;
        }
#pragma unroll
        for (int gg = 0; gg < 4; ++gg) {
            int idx = tid + gg * 256;
            int row = idx >> 3, g = idx & 7;
            int kk = k0 + g * 8;
            float v[8]; ld8g(W_embed + row * 300 + kk, kk, v);
            uint4 pk = { pk2(v[0], v[1]), pk2(v[2], v[3]), pk2(v[4], v[5]), pk2(v[6], v[7]) };
            *(uint4*)&sWc[row * 64 + ((g ^ (row & 7)) << 3)] = pk;
        }
        __syncthreads();
#pragma unroll
        for (int ksb = 0; ksb < 2; ++ksb) {
            int g = ksb * 4 + quad;
            bf16x8 av = *(const bf16x8*)&sVc[l15 * 64 + ((g ^ (l15 & 7)) << 3)];
#pragma unroll
            for (int n = 0; n < 2; ++n) {
                int br = nh * 32 + n * 16 + l15;
                bf16x8 bv = *(const bf16x8*)&sWc[br * 64 + ((g ^ (br & 7)) << 3)];
                accA[n] = __builtin_amdgcn_mfma_f32_16x16x32_bf16(av, bv, accA[n], 0, 0, 0);
            }
        }
        __syncthreads();   // WAR on chunk buffers
    }

    // ---- + b_embed, pair-packed transpose into sT ----
    {
        const int odd = l15 & 1;
#pragma unroll
        for (int n = 0; n < 2; ++n) {
            float bb = b_embed[nh * 32 + n * 16 + l15];
            float v0 = accA[n][0] + bb, v1 = accA[n][1] + bb;
            float v2 = accA[n][2] + bb, v3 = accA[n][3] + bb;
            float t0_ = __shfl_xor(v0, 1), t1_ = __shfl_xor(v1, 1);
            float t2_ = __shfl_xor(v2, 1), t3_ = __shfl_xor(v3, 1);
            float lo0 = odd ? t2_ : v0, hi0 = odd ? v2 : t0_;
            float lo1 = odd ? t3_ : v1, hi1 = odd ? v3 : t1_;
            int r0 = quad * 4 + (odd ? 2 : 0);
            int r1 = r0 + 1;
            int ce = nh * 32 + n * 16 + (l15 & ~1);
            *(uint32*)&sT[r0 * 128 + (((ce >> 3) ^ (r0 & 7)) << 3) + (ce & 7)] = pk2(lo0, hi0);
            *(uint32*)&sT[r1 * 128 + (((ce >> 3) ^ (r1 & 7)) << 3) + (ce & 7)] = pk2(lo1, hi1);
        }
    }
    __syncthreads();   // sT (cross-wave k-reads) + sW0 visible

    // ---- stage B: E1 = emb @ W0^T (K=128) ----
    f32x4 accB[2];
#pragma unroll
    for (int n = 0; n < 2; ++n) { accB[n][0] = 0.f; accB[n][1] = 0.f; accB[n][2] = 0.f; accB[n][3] = 0.f; }
#pragma unroll
    for (int ks = 0; ks < 4; ++ks) {
        int g = ks * 4 + quad;
        bf16x8 av = *(const bf16x8*)&sT[l15 * 128 + ((g ^ (l15 & 7)) << 3)];
#pragma unroll
        for (int n = 0; n < 2; ++n) {
            int br = nh * 32 + n * 16 + l15;
            bf16x8 bv = *(const bf16x8*)&sW0[br * 128 + ((g ^ (br & 7)) << 3)];
            accB[n] = __builtin_amdgcn_mfma_f32_16x16x32_bf16(av, bv, accB[n], 0, 0, 0);
        }
    }

    // ---- epilogue: E1h bf16 + t0 = x0*E1 (rows d < 1000 only) ----
#pragma unroll
    for (int i = 0; i < 4; ++i) {
        int r = quad * 4 + i;
        int d = dbase + r;
        if (d < D_N) {
            float x0 = (d < 800) ? Xn[d] : Xc[d - 800];
#pragma unroll
            for (int n = 0; n < 2; ++n) {
                int col = nh * 32 + n * 16 + l15;
                float e1 = accB[n][i];
                E1h[d * H_N + col] = f2bf(e1);
                t0[d * H_N + col] = x0 * e1;
            }
        }
    }
}

// ---------------------------------------------------------------------------
// k_layer: batch-0 GCN layer, fused agg + next GEMM. 1000 blocks x 128.
// ---------------------------------------------------------------------------
__global__ void k_layer(const float* __restrict__ t_in, const float* __restrict__ bias,
                        const float* __restrict__ Wn, const int* __restrict__ deg,
                        const int* __restrict__ es,
                        float* __restrict__ t_out, float* out, int pool) {
    __shared__ float sh[128];
    int d = blockIdx.x, e = threadIdx.x;
    float di = rsqrtf(1.f + (float)deg[d]);
    float acc = t_in[d * H_N + e] * di * di;
    int n = deg[d]; if (n > CAP) n = CAP;
    const int* row = es + d * CAP;
    int i = 0;
    for (; i + 4 <= n; i += 4) {
        int a0 = row[i], a1 = row[i + 1], a2 = row[i + 2], a3 = row[i + 3];
        float c0 = rsqrtf(1.f + (float)deg[a0]);
        float c1 = rsqrtf(1.f + (float)deg[a1]);
        float c2 = rsqrtf(1.f + (float)deg[a2]);
        float c3 = rsqrtf(1.f + (float)deg[a3]);
        acc += di * (c0 * t_in[a0 * H_N + e] + c1 * t_in[a1 * H_N + e] +
                     c2 * t_in[a2 * H_N + e] + c3 * t_in[a3 * H_N + e]);
    }
    for (; i < n; ++i) {
        int s = row[i];
        acc += di * rsqrtf(1.f + (float)deg[s]) * t_in[s * H_N + e];
    }
    float h = rl(acc + bias[e]);
    if (pool) { atomicAdd(&out[e], h * (1.0f / 1000.0f)); return; }
    sh[e] = h;
    __syncthreads();
    const float4* hr = (const float4*)sh;
    const float4* wr = (const float4*)(Wn + e * 128);
    float s = 0.f;
#pragma unroll 8
    for (int k = 0; k < 32; ++k) {
        float4 a = hr[k], w = wr[k];
        s += a.x * w.x + a.y * w.y + a.z * w.z + a.w * w.w;
    }
    t_out[d * H_N + e] = s;
}

// ---------------------------------------------------------------------------
// k_big: blocks [0,125)   : edge scatter (early dispatch -> overlaps compute)
//        blocks [125,1149): 1024 compute units = 128 batch-PAIRS x 8 chunks.
// R9-proven champion + R12 micro-tweak: E1h/b0 loads for GEMM1 hoisted ahead
// of the ks-loop (8 outstanding uint4 loads, one vmcnt wait instead of four;
// occupancy is LDS-bound at 2 blocks/CU so +VGPR is free).
// Pairing: batches bi0=1+2p, bi1=2+2p share all E1h rows / weight frags /
// biases for the same 128-row chunk -> each LDS B-read feeds 4 MFMAs.
// W1->sA, W2->sB (64KB, 2 blocks/CU); per-batch transpose reuses the same
// 8KB/wave region of sA serially (in-wave DS ordering).
// MFMA 16x16x32 bf16 layouts (m89/m120-verified):
//   A/B: lane holds M[row=lane&15][k=quad*8+j]; C/D: col=lane&15, row=quad*4+reg
// ---------------------------------------------------------------------------
__global__ __launch_bounds__(256, 2)
void k_big(const float* __restrict__ Xn, const float* __restrict__ Xc,
           const u16* __restrict__ E1h, const u16* __restrict__ w1h,
           const u16* __restrict__ w2h, const float* __restrict__ b0,
           const float* __restrict__ b1, const float* __restrict__ b2,
           const int* __restrict__ eidx, int* __restrict__ deg,
           int* __restrict__ es, float* __restrict__ out) {
    __shared__ __align__(16) u16 sA[128 * 128];   // 32 KiB: W1, then transpose buf
    __shared__ __align__(16) u16 sB[128 * 128];   // 32 KiB: W2 (persistent)

    if (blockIdx.x < 125) {
        int e = blockIdx.x * 256 + threadIdx.x;            // 0..31999 exact
        int s = eidx[e], t = eidx[E_N + e];
        int pos = atomicAdd(&deg[t], 1);
        if (pos < CAP) es[t * CAP + pos] = s;
        return;
    }
    const int cb = blockIdx.x - 125;
    const int tid = threadIdx.x;
    const int wave = tid >> 6, lane = tid & 63;
    const int quad = lane >> 4, l15 = lane & 15;
    const int pr = cb >> 3;                    // pair index 0..127
    const int bi0 = 1 + 2 * pr;                // odd batches 1..255
    const int bi1 = 2 + 2 * pr;                // even batches 2..256(invalid last)
    const int wr1 = bi1 < B_N;
    const int bi1c = wr1 ? bi1 : B_N - 1;
    const int mbase = ((cb & 7) << 7) + wave * 32;
    u16* hw = sA + wave * (32 * 128);   // per-wave 8KB transpose region

    // ---- stage W1 -> sA, W2 -> sB (swizzled granules) ----
    {
        const uint4* w1v = (const uint4*)w1h;
        const uint4* w2v = (const uint4*)w2h;
#pragma unroll
        for (int i = 0; i < 8; ++i) {
            int idx = tid + i * 256;
            int row = idx >> 4, g = idx & 15;
            int off = row * 128 + ((g ^ (row & 7)) << 3);
            *(uint4*)&sA[off] = w1v[idx];
            *(uint4*)&sB[off] = w2v[idx];
        }
    }

    const int rA = mbase + l15;  const int rAc = rA < D_N ? rA : D_N - 1;
    const int rB = rA + 16;      const int rBc = rB < D_N ? rB : D_N - 1;
    const float xv0A = (rAc < 800) ? Xn[bi0 * 800 + rAc] : Xc[bi0 * 200 + rAc - 800];
    const float xv0B = (rBc < 800) ? Xn[bi0 * 800 + rBc] : Xc[bi0 * 200 + rBc - 800];
    const float xv1A = (rAc < 800) ? Xn[bi1c * 800 + rAc] : Xc[bi1c * 200 + rAc - 800];
    const float xv1B = (rBc < 800) ? Xn[bi1c * 800 + rBc] : Xc[bi1c * 200 + rBc - 800];

    // ---- R12 tweak: hoist all E1h rows + b0 slices (8+8 loads in flight) ----
    uint4 eAh[4], eBh[4];
    float4 blh[4], bhh[4];
#pragma unroll
    for (int ks = 0; ks < 4; ++ks) {
        const int k8 = ks * 4 + quad;
        eAh[ks] = *(const uint4*)(E1h + rAc * H_N + k8 * 8);
        eBh[ks] = *(const uint4*)(E1h + rBc * H_N + k8 * 8);
        blh[ks] = *(const float4*)(b0 + k8 * 8);
        bhh[ks] = *(const float4*)(b0 + k8 * 8 + 4);
    }

    f32x4 acc0[2][8], acc1[2][8];
#pragma unroll
    for (int rt = 0; rt < 2; ++rt)
#pragma unroll
        for (int n = 0; n < 8; ++n) {
            acc0[rt][n][0] = 0.f; acc0[rt][n][1] = 0.f; acc0[rt][n][2] = 0.f; acc0[rt][n][3] = 0.f;
            acc1[rt][n][0] = 0.f; acc1[rt][n][1] = 0.f; acc1[rt][n][2] = 0.f; acc1[rt][n][3] = 0.f;
        }

    __syncthreads();   // sA (W1) + sB (W2) staged

    // ---- GEMM1: h2 = relu(x*E1+b0) @ W1^T for BOTH batches (B from sA) ----
#pragma unroll
    for (int ks = 0; ks < 4; ++ks) {
        const int k8 = ks * 4 + quad;
        bf16x8 a0A = mk_h1(xv0A, eAh[ks], blh[ks], bhh[ks]);
        bf16x8 a0B = mk_h1(xv0B, eBh[ks], blh[ks], bhh[ks]);
        bf16x8 a1A = mk_h1(xv1A, eAh[ks], blh[ks], bhh[ks]);
        bf16x8 a1B = mk_h1(xv1B, eBh[ks], blh[ks], bhh[ks]);
#pragma unroll
        for (int n = 0; n < 8; ++n) {
            int br = n * 16 + l15;
            bf16x8 bw = *(const bf16x8*)&sA[br * 128 + ((k8 ^ (br & 7)) << 3)];
            acc0[0][n] = __builtin_amdgcn_mfma_f32_16x16x32_bf16(a0A, bw, acc0[0][n], 0, 0, 0);
            acc0[1][n] = __builtin_amdgcn_mfma_f32_16x16x32_bf16(a0B, bw, acc0[1][n], 0, 0, 0);
            acc1[0][n] = __builtin_amdgcn_mfma_f32_16x16x32_bf16(a1A, bw, acc1[0][n], 0, 0, 0);
            acc1[1][n] = __builtin_amdgcn_mfma_f32_16x16x32_bf16(a1B, bw, acc1[1][n], 0, 0, 0);
        }
    }

    __syncthreads();   // all waves done reading W1 from sA

    const int rem = D_N - mbase;   // >= 8 always
    const int odd = l15 & 1;

    // ---- per-batch: transpose -> GEMM2 -> epilogue (serial, shared 8KB buf) ----
#pragma unroll
    for (int bsel = 0; bsel < 2; ++bsel) {
        f32x4 (*accp)[8] = bsel ? acc1 : acc0;
        int bi = bsel ? bi1 : bi0;
        int wr = bsel ? wr1 : 1;

        // +b1, relu, pair-packed transpose into own 8KB region of sA
#pragma unroll
        for (int rt = 0; rt < 2; ++rt)
#pragma unroll
            for (int n = 0; n < 8; ++n) {
                float bg = b1[n * 16 + l15];
                float v0 = rl(accp[rt][n][0] + bg);
                float v1 = rl(accp[rt][n][1] + bg);
                float v2 = rl(accp[rt][n][2] + bg);
                float v3 = rl(accp[rt][n][3] + bg);
                float t0_ = __shfl_xor(v0, 1), t1_ = __shfl_xor(v1, 1);
                float t2_ = __shfl_xor(v2, 1), t3_ = __shfl_xor(v3, 1);
                float lo0 = odd ? t2_ : v0, hi0 = odd ? v2 : t0_;
                float lo1 = odd ? t3_ : v1, hi1 = odd ? v3 : t1_;
                int r0 = rt * 16 + quad * 4 + (odd ? 2 : 0);
                int r1 = r0 + 1;
                int ce = n * 16 + (l15 & ~1);
                *(uint32*)&hw[r0 * 128 + (((ce >> 3) ^ (r0 & 7)) << 3) + (ce & 7)] = pk2(lo0, hi0);
                *(uint32*)&hw[r1 * 128 + (((ce >> 3) ^ (r1 & 7)) << 3) + (ce & 7)] = pk2(lo1, hi1);
            }

        // GEMM2: h3 = h2 @ W2^T (A: own sA region; B: sB) — reuse accp
#pragma unroll
        for (int rt = 0; rt < 2; ++rt)
#pragma unroll
            for (int n = 0; n < 8; ++n) {
                accp[rt][n][0] = 0.f; accp[rt][n][1] = 0.f;
                accp[rt][n][2] = 0.f; accp[rt][n][3] = 0.f;
            }
#pragma unroll
        for (int ks = 0; ks < 4; ++ks) {
            int k8 = ks * 4 + quad;
            int m0 = l15, m1 = 16 + l15;
            bf16x8 a0 = *(const bf16x8*)&hw[m0 * 128 + ((k8 ^ (m0 & 7)) << 3)];
            bf16x8 a1 = *(const bf16x8*)&hw[m1 * 128 + ((k8 ^ (m1 & 7)) << 3)];
#pragma unroll
            for (int n = 0; n < 8; ++n) {
                int br = n * 16 + l15;
                bf16x8 bw = *(const bf16x8*)&sB[br * 128 + ((k8 ^ (br & 7)) << 3)];
                accp[0][n] = __builtin_amdgcn_mfma_f32_16x16x32_bf16(a0, bw, accp[0][n], 0, 0, 0);
                accp[1][n] = __builtin_amdgcn_mfma_f32_16x16x32_bf16(a1, bw, accp[1][n], 0, 0, 0);
            }
        }

        // +b2, relu, masked column-sum, quad-reduce, one atomic per col
#pragma unroll
        for (int n = 0; n < 8; ++n) {
            float bg = b2[n * 16 + l15];
            float cs = 0.f;
#pragma unroll
            for (int rt = 0; rt < 2; ++rt)
#pragma unroll
                for (int i = 0; i < 4; ++i) {
                    int r32 = rt * 16 + quad * 4 + i;
                    float v = rl(accp[rt][n][i] + bg);
                    if (r32 < rem) cs += v;
                }
            cs += __shfl_xor(cs, 16);
            cs += __shfl_xor(cs, 32);
            if (lane < 16 && wr)
                atomicAdd(&out[bi * H_N + n * 16 + l15], cs * (1.0f / 1000.0f));
        }
    }
}

// ---------------------------------------------------------------------------
extern "C" void kernel_launch(void* const* d_in, const int* in_sizes, int n_in,
                              void* d_out, int out_size, void* d_ws, size_t ws_size,
                              hipStream_t stream) {
    const float* Xn = (const float*)d_in[0];
    const float* Xc = (const float*)d_in[1];
    const float* V = (const float*)d_in[2];
    const int* eidx = (const int*)d_in[3];
    const float* W_embed = (const float*)d_in[4];
    const float* b_embed = (const float*)d_in[5];
    const float* W0 = (const float*)d_in[6];
    const float* b0 = (const float*)d_in[7];
    const float* W1 = (const float*)d_in[8];
    const float* b1 = (const float*)d_in[9];
    const float* W2 = (const float*)d_in[10];
    const float* b2 = (const float*)d_in[11];
    float* out = (float*)d_out;

    char* p = (char*)d_ws;
    auto alloc = [&](size_t bytes) -> char* {
        char* r = p;
        p += (bytes + 255) & ~(size_t)255;
        return r;
    };
    u16*   E1h = (u16*)  alloc(D_N * H_N * 2);
    float* t0  = (float*)alloc(D_N * H_N * 4);
    float* t1  = (float*)alloc(D_N * H_N * 4);
    float* t2  = (float*)alloc(D_N * H_N * 4);
    u16*   w1h = (u16*)  alloc(H_N * H_N * 2);
    u16*   w2h = (u16*)  alloc(H_N * H_N * 2);
    int*   deg = (int*)  alloc(D_N * 4);
    int*   es  = (int*)  alloc(D_N * CAP * 4);

    k_prep<<<dim3(256), dim3(256), 0, stream>>>(V, W_embed, b_embed, W0, Xn, Xc,
                                                W1, W2, deg, w1h, w2h, E1h, t0, out);
    k_big<<<dim3(1149), dim3(256), 0, stream>>>(Xn, Xc, E1h, w1h, w2h, b0, b1, b2,
                                                eidx, deg, es, out);
    k_layer<<<dim3(1000), dim3(128), 0, stream>>>(t0, b0, W1, deg, es, t1, out, 0);
    k_layer<<<dim3(1000), dim3(128), 0, stream>>>(t1, b1, W2, deg, es, t2, out, 0);
    k_layer<<<dim3(1000), dim3(128), 0, stream>>>(t2, b2, (const float*)nullptr, deg, es,
                                                  (float*)nullptr, out, 1);
}